// Round 13
// baseline (132.975 us; speedup 1.0000x reference)
//
#include <hip/hip_runtime.h>
#include <hip/hip_fp16.h>
#include <math.h>

// SSIM loss, fully wave-independent MFMA pipeline. No LDS staging, no
// barriers. Each wave owns a 16-col x 32-row output slice of a 64x32 tile:
//   1) A-fragments loaded DIRECTLY from global: lane(cl,am) reads rows
//      R0-5+16mt+cl, cols C0+16w-8+8am..+7 (8 f32 = 2 float4). Builds
//      {x, y, x2+y2, xy} f16 fragments in-register.
//   2) H-blur: 12 banded K=32 MFMAs (Bh[j]=g[8am+j-cl-3], validated r11).
//      D layout: row=4am+reg, col=cl.
//   3) V-blur: D's (am,reg) packing == B-operand packing of 16x16x16 MFMA
//      (k=4am+j, n=cl) -> chain through registers, no transpose, no LDS.
//      Band split over two K=16 windows: out = Av1*B1 + Av2*B2,
//      Av1[j]=g[4am+j-cl], Av2[j]=g[4am+j+16-cl]; B1=f16(Dh[mtv]),
//      B2=f16(Dh[mtv+1]).
//   4) SSIM map on 8 register pixels (row 16mtv+4am+j, col 16w+cl) -> lsum.
// Edge tiles (R0 0/480, col-slice 0/496) take a wave-uniform masked path.
// Zero-padding == zero inputs (products of zeros) == reference conv pad.

#define HH 512
#define WW 512
#define HW (HH*WW)
#define NPLANES 48
#define G_TILES 6
#define NBLOCKS 1024           // 6144 tiles / 6

typedef _Float16 f16x8 __attribute__((ext_vector_type(8)));
typedef _Float16 f16x4 __attribute__((ext_vector_type(4)));
typedef float f32x4 __attribute__((ext_vector_type(4)));

struct WParam { float A, B; };

__global__ void ssim_init_out(float* out) { out[0] = 1.0f; }

__device__ __forceinline__ f16x8 cvt8(float4 a, float4 b) {
    f16x8 h;
    h[0]=(_Float16)a.x; h[1]=(_Float16)a.y; h[2]=(_Float16)a.z; h[3]=(_Float16)a.w;
    h[4]=(_Float16)b.x; h[5]=(_Float16)b.y; h[6]=(_Float16)b.z; h[7]=(_Float16)b.w;
    return h;
}

__global__ __launch_bounds__(256, 4)
void ssim_mfma(const float* __restrict__ img, const float* __restrict__ tgt,
               float* __restrict__ out, WParam wp) {
    __shared__ float wsum[4];

    const int tid  = threadIdx.x;
    const int wid  = tid >> 6;
    const int lane = tid & 63;
    const int cl   = lane & 15;
    const int am   = lane >> 4;

    // ---- per-lane weight fragments ----
    f16x8 Bh;
    #pragma unroll
    for (int j = 0; j < 8; ++j) {
        int ih = 8*am + j - cl - 3;
        float t = (float)(ih - 5);
        Bh[j] = ((unsigned)ih <= 10u) ? (_Float16)(wp.A * exp2f(-wp.B*t*t))
                                      : (_Float16)0.f;
    }
    f16x4 Av1, Av2;
    #pragma unroll
    for (int j = 0; j < 4; ++j) {
        int k = 4*am + j;
        int i1 = k - cl;
        float t1 = (float)(i1 - 5);
        Av1[j] = ((unsigned)i1 <= 10u) ? (_Float16)(wp.A * exp2f(-wp.B*t1*t1))
                                       : (_Float16)0.f;
        int i2 = k + 16 - cl;
        float t2 = (float)(i2 - 5);
        Av2[j] = ((unsigned)i2 <= 10u) ? (_Float16)(wp.A * exp2f(-wp.B*t2*t2))
                                       : (_Float16)0.f;
    }

    const float C1 = 1e-4f, C2 = 9e-4f;
    float lsum = 0.f;

    for (int g = 0; g < G_TILES; ++g) {
        const int tlin = blockIdx.x * G_TILES + g;
        const int p    = tlin >> 7;
        const int rem  = tlin & 127;
        const int R0   = (rem >> 3) * 32;
        const int C0   = (rem & 7) * 64;
        const float* ip = img + (size_t)p * HW;
        const float* tp = tgt + (size_t)p * HW;
        const int cw   = C0 + 16*wid;       // wave's out-col base
        const int colb = cw - 8 + 8*am;     // lane's first input col

        f16x8 hx[3], hy[3];
        const bool edge = (R0 == 0) | (R0 == 480) | (cw == 0) | (cw == 496);
        if (!edge) {
            #pragma unroll
            for (int mt = 0; mt < 3; ++mt) {
                int r = R0 - 5 + 16*mt + cl;
                const float* xr = ip + (size_t)r * WW + colb;
                const float* yr = tp + (size_t)r * WW + colb;
                float4 x0 = *(const float4*)(xr);
                float4 x1 = *(const float4*)(xr + 4);
                float4 y0 = *(const float4*)(yr);
                float4 y1 = *(const float4*)(yr + 4);
                hx[mt] = cvt8(x0, x1);
                hy[mt] = cvt8(y0, y1);
            }
        } else {
            const bool cv0 = (unsigned)colb <= 508u;
            const bool cv1 = (unsigned)(colb + 4) <= 508u;
            const int cb0 = cv0 ? colb : 0;
            const int cb1 = cv1 ? colb + 4 : 0;
            const float4 z = make_float4(0.f, 0.f, 0.f, 0.f);
            #pragma unroll
            for (int mt = 0; mt < 3; ++mt) {
                int r = R0 - 5 + 16*mt + cl;
                bool rv = (unsigned)r < (unsigned)HH;
                size_t ro = (size_t)(rv ? r : 0) * WW;
                const float* xr = ip + ro;
                const float* yr = tp + ro;
                float4 x0 = (rv && cv0) ? *(const float4*)(xr + cb0) : z;
                float4 x1 = (rv && cv1) ? *(const float4*)(xr + cb1) : z;
                float4 y0 = (rv && cv0) ? *(const float4*)(yr + cb0) : z;
                float4 y1 = (rv && cv1) ? *(const float4*)(yr + cb1) : z;
                hx[mt] = cvt8(x0, x1);
                hy[mt] = cvt8(y0, y1);
            }
        }

        // ---- H-blur: 12 banded K=32 MFMAs ----
        f32x4 Dh[4][3];
        #pragma unroll
        for (int mt = 0; mt < 3; ++mt) {
            f16x8 hs = hx[mt]*hx[mt] + hy[mt]*hy[mt];
            f16x8 hp = hx[mt]*hy[mt];
            f32x4 zz = {0.f, 0.f, 0.f, 0.f};
            Dh[0][mt] = __builtin_amdgcn_mfma_f32_16x16x32_f16(hx[mt], Bh, zz, 0, 0, 0);
            Dh[1][mt] = __builtin_amdgcn_mfma_f32_16x16x32_f16(hy[mt], Bh, zz, 0, 0, 0);
            Dh[2][mt] = __builtin_amdgcn_mfma_f32_16x16x32_f16(hs,     Bh, zz, 0, 0, 0);
            Dh[3][mt] = __builtin_amdgcn_mfma_f32_16x16x32_f16(hp,     Bh, zz, 0, 0, 0);
        }

        // ---- V-blur (register-chained) + SSIM ----
        #pragma unroll
        for (int mtv = 0; mtv < 2; ++mtv) {
            f32x4 accv[4];
            #pragma unroll
            for (int q = 0; q < 4; ++q) {
                f16x4 B1, B2;
                #pragma unroll
                for (int j = 0; j < 4; ++j) {
                    B1[j] = (_Float16)Dh[q][mtv][j];
                    B2[j] = (_Float16)Dh[q][mtv+1][j];
                }
                f32x4 zz = {0.f, 0.f, 0.f, 0.f};
                f32x4 acc = __builtin_amdgcn_mfma_f32_16x16x16f16(Av2, B2, zz, 0, 0, 0);
                accv[q]   = __builtin_amdgcn_mfma_f32_16x16x16f16(Av1, B1, acc, 0, 0, 0);
            }
            #pragma unroll
            for (int j = 0; j < 4; ++j) {
                float mu1 = accv[0][j], mu2 = accv[1][j];
                float bss = accv[2][j], bxy = accv[3][j];
                float mu1s = mu1*mu1, mu2s = mu2*mu2, mu12 = mu1*mu2;
                float ssum = bss - mu1s - mu2s;
                float s12  = bxy - mu12;
                float num = (2.f*mu12 + C1) * (2.f*s12 + C2);
                float den = (mu1s + mu2s + C1) * (ssum + C2);
                lsum = fmaf(num, __builtin_amdgcn_rcpf(den), lsum);
            }
        }
    }

    // ---- block reduction + one atomic ----
    for (int off = 32; off > 0; off >>= 1)
        lsum += __shfl_down(lsum, off, 64);
    if (lane == 0) wsum[wid] = lsum;
    __syncthreads();
    if (tid == 0) {
        float bsum = wsum[0] + wsum[1] + wsum[2] + wsum[3];
        const float invN = 1.0f / (float)((size_t)NPLANES * HH * WW);
        atomicAdd(out, -bsum * invN);
    }
}

extern "C" void kernel_launch(void* const* d_in, const int* in_sizes, int n_in,
                              void* d_out, int out_size, void* d_ws, size_t ws_size,
                              hipStream_t stream) {
    const float* img = (const float*)d_in[0];
    const float* tgt = (const float*)d_in[1];
    float* out = (float*)d_out;

    // g[i] = exp(-(i-5)^2/4.5)/s = A * 2^(-B*(i-5)^2)
    double s = 0.0;
    for (int i = 0; i < 11; ++i) {
        double d = (double)(i - 5);
        s += exp(-(d * d) / 4.5);
    }
    WParam wp;
    wp.A = (float)(1.0 / s);
    wp.B = (float)(M_LOG2E / 4.5);

    ssim_init_out<<<1, 1, 0, stream>>>(out);
    ssim_mfma<<<NBLOCKS, 256, 0, stream>>>(img, tgt, out, wp);
}

// Round 14
// 40.277 us; speedup vs baseline: 3.3015x; 3.3015x over previous
//
#include <hip/hip_runtime.h>
#include <hip/hip_fp16.h>
#include <math.h>

// SSIM loss: coalesced LDS staging (r12) + register-chained MFMA blurs (r13).
// Per 64x32 tile:
//   ph1: write prefetched {x,y} regs as f16 planes {x,y} (2 planes only);
//        issue next tile's global loads (in flight across raw s_barriers).
//   compute (per wave, cols 16w..16w+15, NO LDS writes):
//     - 6 ds_read_b128: hx[mt],hy[mt] rows 16mt+cl, bytes 32w+16am
//     - s,p derived in packed f16; 12 banded K=32 H-MFMAs (Bh[j]=g[8am+j-cl-3])
//     - V-blur register-chained: H-D fragment == 16x16x16 B fragment;
//       out = Av1*B1 + Av2*B2, Av1[j]=g[4am+j-cl], Av2[j]=g[4am+j+16-cl]
//       (both validated r13, absmax 0.0); SSIM on 8 reg pixels -> lsum.
//   2 raw barriers/tile (lgkmcnt(0)+s_barrier+sched_barrier(0), r12 protocol).
// LDS 19968 B, G_TILES=6, 1024 blocks = exactly 4/CU. Zero-pad: rows 42-47 /
// cols 80-103 zero-init'd, never written; V-weights for staged rows 42-47
// provably zero (i2>=11); finite*0=0 invariant (r7-r12).

#define HH 512
#define WW 512
#define HW (HH*WW)
#define NPLANES 48
#define G_TILES 6
#define NBLOCKS 1024           // 6144 tiles / 6

typedef _Float16 f16x8 __attribute__((ext_vector_type(8)));
typedef _Float16 f16x4 __attribute__((ext_vector_type(4)));
typedef float f32x4 __attribute__((ext_vector_type(4)));

#define RAW_STRIDE 208         // bytes per staged row (104 f16; 80 used)
#define RAW_PLANE  9984        // 48*208; x at 0, y at RAW_PLANE
#define LDS_TOTAL  19968       // 2 planes

struct WParam { float A, B; };

__global__ void ssim_init_out(float* out) { out[0] = 1.0f; }

__device__ __forceinline__ void barrier_nodrain() {
    asm volatile("s_waitcnt lgkmcnt(0)" ::: "memory");
    __builtin_amdgcn_s_barrier();
    __builtin_amdgcn_sched_barrier(0);
}

__global__ __launch_bounds__(256, 4)
void ssim_mfma(const float* __restrict__ img, const float* __restrict__ tgt,
               float* __restrict__ out, WParam wp) {
    __shared__ alignas(16) char lds[LDS_TOTAL];
    __shared__ float wsum[4];

    const int tid  = threadIdx.x;
    const int wid  = tid >> 6;
    const int lane = tid & 63;
    const int cl   = lane & 15;
    const int am   = lane >> 4;

    // fixed 2 staging items per thread (420 = 256 + 164)
    const int it0 = tid,       ir0 = it0 / 10, ig0 = it0 - 10 * ir0;
    const int it1 = tid + 256, ir1 = it1 / 10, ig1 = it1 - 10 * ir1;
    const bool has1 = (tid < 164);

    float4 Xa[2], Xb[2], Ya[2], Yb[2];

    auto load_tile = [&](int tlin) {
        const int p   = tlin >> 7;
        const int rem = tlin & 127;
        const int R0  = (rem >> 3) * 32;
        const int C0  = (rem & 7) * 64;
        const float* ip = img + (size_t)p * HW;
        const float* tp = tgt + (size_t)p * HW;
        #pragma unroll
        for (int s = 0; s < 2; ++s) {
            if (s == 1 && !has1) break;
            int r   = s ? ir1 : ir0;
            int grp = s ? ig1 : ig0;
            int gr  = R0 - 5 + r;
            int gc0 = C0 - 8 + grp * 8;
            float4 xa = make_float4(0.f,0.f,0.f,0.f), xb = xa, ya = xa, yb = xa;
            if ((unsigned)gr < (unsigned)HH) {
                const float* xr = ip + (size_t)gr * WW;
                const float* yr = tp + (size_t)gr * WW;
                if ((unsigned)gc0 <= (unsigned)(WW - 4)) {
                    xa = *(const float4*)(xr + gc0);
                    ya = *(const float4*)(yr + gc0);
                }
                if ((unsigned)(gc0 + 4) <= (unsigned)(WW - 4)) {
                    xb = *(const float4*)(xr + gc0 + 4);
                    yb = *(const float4*)(yr + gc0 + 4);
                }
            }
            Xa[s] = xa; Xb[s] = xb; Ya[s] = ya; Yb[s] = yb;
        }
    };

    auto write_tile = [&]() {
        #pragma unroll
        for (int s = 0; s < 2; ++s) {
            if (s == 1 && !has1) break;
            int r   = s ? ir1 : ir0;
            int grp = s ? ig1 : ig0;
            f16x8 hx, hy;
            hx[0]=(_Float16)Xa[s].x; hx[1]=(_Float16)Xa[s].y;
            hx[2]=(_Float16)Xa[s].z; hx[3]=(_Float16)Xa[s].w;
            hx[4]=(_Float16)Xb[s].x; hx[5]=(_Float16)Xb[s].y;
            hx[6]=(_Float16)Xb[s].z; hx[7]=(_Float16)Xb[s].w;
            hy[0]=(_Float16)Ya[s].x; hy[1]=(_Float16)Ya[s].y;
            hy[2]=(_Float16)Ya[s].z; hy[3]=(_Float16)Ya[s].w;
            hy[4]=(_Float16)Yb[s].x; hy[5]=(_Float16)Yb[s].y;
            hy[6]=(_Float16)Yb[s].z; hy[7]=(_Float16)Yb[s].w;
            char* base = lds + r * RAW_STRIDE + grp * 16;
            *(f16x8*)(base + 0*RAW_PLANE) = hx;
            *(f16x8*)(base + 1*RAW_PLANE) = hy;
        }
    };

    const int base_t = blockIdx.x * G_TILES;
    load_tile(base_t);                 // prologue prefetch (overlaps init)

    // ---- one-time LDS zero-init (pad rows/cols forever zero) ----
    for (int i = tid; i < LDS_TOTAL / 4; i += 256)
        ((float*)lds)[i] = 0.f;

    // ---- per-lane weight fragments ----
    f16x8 Bh;
    #pragma unroll
    for (int j = 0; j < 8; ++j) {
        int ih = 8*am + j - cl - 3;
        float t = (float)(ih - 5);
        Bh[j] = ((unsigned)ih <= 10u) ? (_Float16)(wp.A * exp2f(-wp.B*t*t))
                                      : (_Float16)0.f;
    }
    f16x4 Av1, Av2;
    #pragma unroll
    for (int j = 0; j < 4; ++j) {
        int k = 4*am + j;
        int i1 = k - cl;
        float t1 = (float)(i1 - 5);
        Av1[j] = ((unsigned)i1 <= 10u) ? (_Float16)(wp.A * exp2f(-wp.B*t1*t1))
                                       : (_Float16)0.f;
        int i2 = k + 16 - cl;
        float t2 = (float)(i2 - 5);
        Av2[j] = ((unsigned)i2 <= 10u) ? (_Float16)(wp.A * exp2f(-wp.B*t2*t2))
                                       : (_Float16)0.f;
    }
    __syncthreads();

    const float C1 = 1e-4f, C2 = 9e-4f;
    float lsum = 0.f;

    for (int g = 0; g < G_TILES; ++g) {
        // ---- phase 1: write prefetched tile to LDS; issue next prefetch ----
        write_tile();
        if (g + 1 < G_TILES) load_tile(base_t + g + 1);
        barrier_nodrain();

        // ---- compute: all-register H+V blur + SSIM (no LDS writes) ----
        {
            const int abase = cl * RAW_STRIDE + 32 * wid + am * 16;
            f16x8 hx3[3], hy3[3];
            #pragma unroll
            for (int mt = 0; mt < 3; ++mt) {
                hx3[mt] = *(const f16x8*)(lds + (16*mt) * RAW_STRIDE + abase);
                hy3[mt] = *(const f16x8*)(lds + RAW_PLANE + (16*mt) * RAW_STRIDE + abase);
            }

            f32x4 accv[4][2];
            #pragma unroll
            for (int q = 0; q < 4; ++q) {
                f32x4 Dh[3];
                #pragma unroll
                for (int mt = 0; mt < 3; ++mt) {
                    f16x8 A = (q == 0) ? hx3[mt]
                            : (q == 1) ? hy3[mt]
                            : (q == 2) ? (f16x8)(hx3[mt]*hx3[mt] + hy3[mt]*hy3[mt])
                                       : (f16x8)(hx3[mt]*hy3[mt]);
                    f32x4 zz = {0.f, 0.f, 0.f, 0.f};
                    Dh[mt] = __builtin_amdgcn_mfma_f32_16x16x32_f16(A, Bh, zz, 0, 0, 0);
                }
                #pragma unroll
                for (int mtv = 0; mtv < 2; ++mtv) {
                    f16x4 B1, B2;
                    #pragma unroll
                    for (int j = 0; j < 4; ++j) {
                        B1[j] = (_Float16)Dh[mtv][j];
                        B2[j] = (_Float16)Dh[mtv+1][j];
                    }
                    f32x4 zz = {0.f, 0.f, 0.f, 0.f};
                    f32x4 acc = __builtin_amdgcn_mfma_f32_16x16x16f16(Av2, B2, zz, 0, 0, 0);
                    accv[q][mtv] = __builtin_amdgcn_mfma_f32_16x16x16f16(Av1, B1, acc, 0, 0, 0);
                }
            }

            #pragma unroll
            for (int mtv = 0; mtv < 2; ++mtv) {
                #pragma unroll
                for (int j = 0; j < 4; ++j) {
                    float mu1 = accv[0][mtv][j], mu2 = accv[1][mtv][j];
                    float bss = accv[2][mtv][j], bxy = accv[3][mtv][j];
                    float mu1s = mu1*mu1, mu2s = mu2*mu2, mu12 = mu1*mu2;
                    float ssum = bss - mu1s - mu2s;
                    float s12  = bxy - mu12;
                    float num = (2.f*mu12 + C1) * (2.f*s12 + C2);
                    float den = (mu1s + mu2s + C1) * (ssum + C2);
                    lsum = fmaf(num, __builtin_amdgcn_rcpf(den), lsum);
                }
            }
        }
        barrier_nodrain();   // all LDS reads done before next ph1 write
    }

    // ---- block reduction + one atomic ----
    for (int off = 32; off > 0; off >>= 1)
        lsum += __shfl_down(lsum, off, 64);
    if (lane == 0) wsum[wid] = lsum;
    __syncthreads();
    if (tid == 0) {
        float bsum = wsum[0] + wsum[1] + wsum[2] + wsum[3];
        const float invN = 1.0f / (float)((size_t)NPLANES * HH * WW);
        atomicAdd(out, -bsum * invN);
    }
}

extern "C" void kernel_launch(void* const* d_in, const int* in_sizes, int n_in,
                              void* d_out, int out_size, void* d_ws, size_t ws_size,
                              hipStream_t stream) {
    const float* img = (const float*)d_in[0];
    const float* tgt = (const float*)d_in[1];
    float* out = (float*)d_out;

    // g[i] = exp(-(i-5)^2/4.5)/s = A * 2^(-B*(i-5)^2)
    double s = 0.0;
    for (int i = 0; i < 11; ++i) {
        double d = (double)(i - 5);
        s += exp(-(d * d) / 4.5);
    }
    WParam wp;
    wp.A = (float)(1.0 / s);
    wp.B = (float)(M_LOG2E / 4.5);

    ssim_init_out<<<1, 1, 0, stream>>>(out);
    ssim_mfma<<<NBLOCKS, 256, 0, stream>>>(img, tgt, out, wp);
}